// Round 4
// baseline (1019.573 us; speedup 1.0000x reference)
//
#include <hip/hip_runtime.h>
#include <math.h>

// Problem constants
#define HID   768
#define DIMD  192
#define NSIG  15
#define BB    32
#define SS    4096
#define SC    128                 // tokens per fused block
#define NCHUNK (SS / SC)          // 32
#define HC    32                  // h-cols staged per iteration
#define NIT   (HID / HC)          // 24 iterations
#define ROWF  36                  // padded LDS row (floats): 144 B, 16-B aligned, phase-clean
#define BUFF  (SC * ROWF)         // 4608 floats per buffer
#define INV_SCALE 0.07216878364870322f   // 1/sqrt(192)
#define LOG_S     8.31776616671934f      // ln(4096)

// Workspace layout (floats)
#define WS_QK   ((size_t)0)                       // [16][768] scaled Q (row 15 = zeros)
#define WS_QB   ((size_t)12288)                   // [16] scaled bias dot (15 = 0)
#define WS_ST   ((size_t)12304)                   // [B][32][15][3] m,l,pa partials
#define WS_WT   ((size_t)58384)                   // [B*32][16][128] unnormalized weights
#define WS_CTXP ((size_t)2155536)                 // [B][32][15][768] ctx partials

// ---------------- Kernel A: Qk[n][h] = (q[n,:].Wk[h,:])/sqrt(d); rows padded to 16 with zeros
__global__ __launch_bounds__(256) void k_qk(const float* __restrict__ q,
                                            const float* __restrict__ Wk,
                                            const float* __restrict__ bk,
                                            float* __restrict__ ws) {
  int idx = blockIdx.x * 256 + threadIdx.x;        // grid 48*256 = 12288 = 16*768
  if (idx < NSIG * HID) {
    int n = idx / HID, h = idx - n * HID;
    const float* qr = q + n * DIMD;
    const float* wr = Wk + h * DIMD;
    float s = 0.f;
    #pragma unroll 4
    for (int d = 0; d < DIMD; ++d) s = fmaf(qr[d], wr[d], s);
    ws[WS_QK + (size_t)n * HID + h] = s * INV_SCALE;
  } else if (idx < 16 * HID) {
    ws[WS_QK + idx] = 0.f;                         // zero row 15
  }
  if (idx < NSIG) {
    const float* qr = q + idx * DIMD;
    float s = 0.f;
    for (int d = 0; d < DIMD; ++d) s = fmaf(qr[d], bk[d], s);
    ws[WS_QB + idx] = s * INV_SCALE;
  } else if (idx < 16) {
    ws[WS_QB + idx] = 0.f;
  }
}

// ---------------- Fused: logits -> wave-local softmax partials -> ctx partials
// Block = (128-token chunk, b), 1024 blocks, 4 blocks/CU (LDS 36.9 KB).
// Wave w owns signals 4w..4w+3; lane l owns tokens l and l+64 (all 128 per wave).
// 2-buffer LDS pipeline, ONE barrier per iteration. Weights go to global scratch.
__global__ __launch_bounds__(256, 4) void k_fused(const float* __restrict__ X,
                                                  const float* __restrict__ qk,
                                                  const float* __restrict__ qb,
                                                  float* __restrict__ stats,
                                                  float* __restrict__ wT,
                                                  float* __restrict__ ctxp) {
  __shared__ __align__(16) float lds[2 * BUFF];    // 36864 B
  const int t = threadIdx.x;
  const int chunk = blockIdx.x, b = blockIdx.y;
  const int w = __builtin_amdgcn_readfirstlane(t >> 6);  // wave id (0..3), uniform
  const int l = t & 63;                                  // lane
  const float* Xb = X + ((size_t)(b * SS + chunk * SC)) * HID;

  // staging map: thread t covers rows r0+32k (k<4), float4-group g of the 32-col chunk
  const int r0 = t >> 3, g = t & 7;

  // ---- Pass A: 2-buffer pipeline, one barrier/iter
  float4 r[4];
  #pragma unroll
  for (int k = 0; k < 4; ++k)
    r[k] = *(const float4*)(Xb + (size_t)(r0 + 32 * k) * HID + 4 * g);
  {
    float* d0 = lds;                                // preamble: stage iter 0 -> buf0
    #pragma unroll
    for (int k = 0; k < 4; ++k)
      *(float4*)(d0 + (r0 + 32 * k) * ROWF + 4 * g) = r[k];
  }

  float acc[4][2];
  #pragma unroll
  for (int i = 0; i < 4; ++i) { acc[i][0] = qb[4 * w + i]; acc[i][1] = qb[4 * w + i]; }

  for (int c = 0; c < NIT; ++c) {
    if (c + 1 < NIT) {                              // prefetch next chunk into regs
      #pragma unroll
      for (int k = 0; k < 4; ++k)
        r[k] = *(const float4*)(Xb + (size_t)(r0 + 32 * k) * HID + (c + 1) * HC + 4 * g);
    }
    __syncthreads();                                // buf[c&1] ready for all waves
    const float* buf = lds + (c & 1) * BUFF;
    #pragma unroll
    for (int half = 0; half < 2; ++half) {
      __align__(16) float xv0[16], xv1[16];
      const float4* p0 = (const float4*)(buf + l * ROWF + half * 16);
      const float4* p1 = (const float4*)(buf + (l + 64) * ROWF + half * 16);
      #pragma unroll
      for (int qd = 0; qd < 4; ++qd) {
        ((float4*)xv0)[qd] = p0[qd];
        ((float4*)xv1)[qd] = p1[qd];
      }
      const float* Qh = qk + c * HC + half * 16;    // wave-uniform -> s_load
      #pragma unroll
      for (int i = 0; i < 4; ++i) {
        const float* Qn = Qh + (size_t)(4 * w + i) * HID;
        #pragma unroll
        for (int j = 0; j < 16; ++j) {
          acc[i][0] = fmaf(xv0[j], Qn[j], acc[i][0]);
          acc[i][1] = fmaf(xv1[j], Qn[j], acc[i][1]);
        }
      }
    }
    if (c + 1 < NIT) {                              // stage prefetched regs -> idle buf
      float* d1 = lds + ((c + 1) & 1) * BUFF;
      #pragma unroll
      for (int k = 0; k < 4; ++k)
        *(float4*)(d1 + (r0 + 32 * k) * ROWF + 4 * g) = r[k];
    }
  }

  // ---- wave-local softmax partials (signals 4w+i over this wave's 128 tokens)
  float* wTb = wT + ((size_t)(b * NCHUNK + chunk)) * 16 * 128;
  #pragma unroll
  for (int i = 0; i < 4; ++i) {
    const int n = 4 * w + i;
    float a0 = acc[i][0], a1 = acc[i][1];
    float m = fmaxf(a0, a1);
    #pragma unroll
    for (int o = 32; o > 0; o >>= 1) m = fmaxf(m, __shfl_xor(m, o, 64));
    float e0 = expf(a0 - m), e1 = expf(a1 - m);
    float ls = e0 + e1, pa = fmaf(e0, a0, e1 * a1);
    #pragma unroll
    for (int o = 32; o > 0; o >>= 1) { ls += __shfl_xor(ls, o, 64); pa += __shfl_xor(pa, o, 64); }
    wTb[n * 128 + l]      = e0;                     // unnormalized weights
    wTb[n * 128 + l + 64] = e1;
    if (l == 0 && n < NSIG) {
      float* st = stats + ((size_t)((b * NCHUNK + chunk) * NSIG + n)) * 3;
      st[0] = m; st[1] = ls; st[2] = pa;
    }
  }
  __syncthreads();                                  // vmem drain + barrier: wT visible

  // ---- Pass B: ctx partials; thread owns h-cols {t, t+256, t+512}; X from L2/L3
  float accB[NSIG * 3];
  #pragma unroll
  for (int i = 0; i < NSIG * 3; ++i) accB[i] = 0.f;
  const float* Xc = Xb + t;

  float xa[12], xb2[12];
  #pragma unroll
  for (int j = 0; j < 4; ++j)
    #pragma unroll
    for (int k = 0; k < 3; ++k)
      xa[j * 3 + k] = Xc[(size_t)j * HID + k * 256];

  #define FMA_GRP(xg, sg)                                             \
    _Pragma("unroll")                                                 \
    for (int n = 0; n < NSIG; ++n) {                                  \
      float4 w4 = *(const float4*)(wTb + n * 128 + (sg) * 4);         \
      accB[n*3+0] = fmaf(w4.x, (xg)[0], accB[n*3+0]);                 \
      accB[n*3+1] = fmaf(w4.x, (xg)[1], accB[n*3+1]);                 \
      accB[n*3+2] = fmaf(w4.x, (xg)[2], accB[n*3+2]);                 \
      accB[n*3+0] = fmaf(w4.y, (xg)[3], accB[n*3+0]);                 \
      accB[n*3+1] = fmaf(w4.y, (xg)[4], accB[n*3+1]);                 \
      accB[n*3+2] = fmaf(w4.y, (xg)[5], accB[n*3+2]);                 \
      accB[n*3+0] = fmaf(w4.z, (xg)[6], accB[n*3+0]);                 \
      accB[n*3+1] = fmaf(w4.z, (xg)[7], accB[n*3+1]);                 \
      accB[n*3+2] = fmaf(w4.z, (xg)[8], accB[n*3+2]);                 \
      accB[n*3+0] = fmaf(w4.w, (xg)[9], accB[n*3+0]);                 \
      accB[n*3+1] = fmaf(w4.w, (xg)[10], accB[n*3+1]);                \
      accB[n*3+2] = fmaf(w4.w, (xg)[11], accB[n*3+2]);                \
    }

  for (int sg = 0; sg < 32; sg += 2) {
    {                                               // prefetch group sg+1
      const float* Xg = Xc + (size_t)(sg + 1) * 4 * HID;
      #pragma unroll
      for (int j = 0; j < 4; ++j)
        #pragma unroll
        for (int k = 0; k < 3; ++k)
          xb2[j * 3 + k] = Xg[(size_t)j * HID + k * 256];
    }
    FMA_GRP(xa, sg)
    if (sg + 2 < 32) {                              // prefetch group sg+2
      const float* Xg = Xc + (size_t)(sg + 2) * 4 * HID;
      #pragma unroll
      for (int j = 0; j < 4; ++j)
        #pragma unroll
        for (int k = 0; k < 3; ++k)
          xa[j * 3 + k] = Xg[(size_t)j * HID + k * 256];
    }
    FMA_GRP(xb2, sg + 1)
  }
  #undef FMA_GRP

  float* dst = ctxp + ((size_t)((b * NCHUNK + chunk) * NSIG)) * HID + t;
  #pragma unroll
  for (int n = 0; n < NSIG; ++n)
    #pragma unroll
    for (int k = 0; k < 3; ++k)
      dst[(size_t)n * HID + k * 256] = accB[n * 3 + k];   // coalesced
}

// ---------------- Final: combine partials, entropy/strength, ctx.Wv, gelu MLP
__global__ __launch_bounds__(256) void k_final(const float* __restrict__ stats,
                                               const float* __restrict__ ctxp,
                                               const float* __restrict__ Wv,
                                               const float* __restrict__ bv,
                                               const float* __restrict__ nullemb,
                                               const float* __restrict__ W1,
                                               const float* __restrict__ b1,
                                               const float* __restrict__ W2,
                                               const float* __restrict__ b2,
                                               float* __restrict__ out) {
  const int blk = blockIdx.x;                  // 0..479
  const int b = blk / NSIG, n = blk - b * NSIG;
  const int t = threadIdx.x;
  __shared__ float alpha[NCHUNK];
  __shared__ float ctx[HID];
  __shared__ float se[DIMD];

  if (t == 0) {
    float mc[NCHUNK], lc[NCHUNK], pc[NCHUNK];
    float m = -1e30f;
    #pragma unroll
    for (int c = 0; c < NCHUNK; ++c) {
      const float* st = stats + ((size_t)((b * NCHUNK + c) * NSIG + n)) * 3;
      mc[c] = st[0]; lc[c] = st[1]; pc[c] = st[2];
      m = fmaxf(m, mc[c]);
    }
    float L = 0.f, PA = 0.f;
    #pragma unroll
    for (int c = 0; c < NCHUNK; ++c) {
      float scl = expf(mc[c] - m);
      L = fmaf(scl, lc[c], L); PA = fmaf(scl, pc[c], PA);
    }
    #pragma unroll
    for (int c = 0; c < NCHUNK; ++c) alpha[c] = expf(mc[c] - m) / L;
    float entropy = m + logf(L) - PA / L;
    out[b * (2 * NSIG) + NSIG + n] = 1.f - entropy / LOG_S;
  }
  __syncthreads();

  #pragma unroll
  for (int k = 0; k < 3; ++k) {
    int h = t + k * 256;
    float s = 0.f;
    #pragma unroll 8
    for (int c = 0; c < NCHUNK; ++c)
      s = fmaf(alpha[c], ctxp[((size_t)((b * NCHUNK + c) * NSIG + n)) * HID + h], s);
    ctx[h] = s;
  }
  __syncthreads();

  if (t < DIMD) {
    float s0 = 0.f, s1 = 0.f, s2 = 0.f, s3 = 0.f;   // 4 partials: break dep chain
    #pragma unroll 4
    for (int h = 0; h < HID; h += 4) {
      s0 = fmaf(ctx[h],     Wv[(size_t)h * DIMD + t],       s0);
      s1 = fmaf(ctx[h + 1], Wv[(size_t)(h + 1) * DIMD + t], s1);
      s2 = fmaf(ctx[h + 2], Wv[(size_t)(h + 2) * DIMD + t], s2);
      s3 = fmaf(ctx[h + 3], Wv[(size_t)(h + 3) * DIMD + t], s3);
    }
    se[t] = bv[t] + ((s0 + s1) + (s2 + s3));
  }
  __syncthreads();

  if (t < 64) {
    float s = b1[t];
    const float* nrow = nullemb + (size_t)n * HID;
    #pragma unroll 4
    for (int i = 0; i < DIMD; ++i) s = fmaf(se[i],   W1[(size_t)i * 64 + t], s);
    #pragma unroll 4
    for (int i = 0; i < DIMD; ++i) s = fmaf(nrow[i], W1[(size_t)(DIMD + i) * 64 + t], s);
    float gl = 0.5f * s * (1.f + erff(s * 0.70710678118654752f));  // exact gelu
    float val = gl * W2[t];
    #pragma unroll
    for (int o = 32; o > 0; o >>= 1) val += __shfl_down(val, o, 64);
    if (t == 0) out[b * (2 * NSIG) + n] = val + b2[0];
  }
}

extern "C" void kernel_launch(void* const* d_in, const int* in_sizes, int n_in,
                              void* d_out, int out_size, void* d_ws, size_t ws_size,
                              hipStream_t stream) {
  const float* X   = (const float*)d_in[0];
  const float* Wk  = (const float*)d_in[1];
  const float* bk  = (const float*)d_in[2];
  const float* Wv  = (const float*)d_in[3];
  const float* bv  = (const float*)d_in[4];
  const float* q   = (const float*)d_in[5];
  const float* nul = (const float*)d_in[6];
  const float* W1  = (const float*)d_in[7];
  const float* b1  = (const float*)d_in[8];
  const float* W2  = (const float*)d_in[9];
  const float* b2  = (const float*)d_in[10];
  float* out = (float*)d_out;
  float* ws  = (float*)d_ws;    // ~56 MB used

  hipLaunchKernelGGL(k_qk, dim3(48), dim3(256), 0, stream, q, Wk, bk, ws);
  hipLaunchKernelGGL(k_fused, dim3(NCHUNK, BB), dim3(256), 0, stream,
                     X, ws + WS_QK, ws + WS_QB, ws + WS_ST, ws + WS_WT, ws + WS_CTXP);
  hipLaunchKernelGGL(k_final, dim3(BB * NSIG), dim3(256), 0, stream,
                     ws + WS_ST, ws + WS_CTXP, Wv, bv, nul, W1, b1, W2, b2, out);
}